// Round 9
// baseline (156.838 us; speedup 1.0000x reference)
//
#include <hip/hip_runtime.h>
#include <stdint.h>

#define N_TOK 8192
#define C_DIM 768
#define E_NUM 8
#define NT2 (C_DIM / 64)      // 12 K-tiles of 64
#define TOTX3 104             // 32 shared + up to 72 expert x-blocks (256-row units)
#define GRID3 312             // TOTX3 * 3 column-tiles; = 8 XCDs * 39
#define XXP3 13               // xx-values per XCD (104/8)

typedef short short8 __attribute__((ext_vector_type(8)));
typedef __bf16 bf16x8 __attribute__((ext_vector_type(8)));
typedef float f32x4 __attribute__((ext_vector_type(4)));

static __device__ __forceinline__ unsigned short f2bf(float f) {
    unsigned u = __float_as_uint(f);
    unsigned r = u + 0x7FFFu + ((u >> 16) & 1u);
    return (unsigned short)(r >> 16);
}
static __device__ __forceinline__ float bf2f(unsigned short h) {
    return __uint_as_float(((unsigned)h) << 16);
}

// ------------- transpose+convert weights: Wt[m][o][i] = W[m][i][o], bf16 -------------
__global__ void wtrans_kernel(const float* __restrict__ wfc, const float* __restrict__ wpj,
                              const float* __restrict__ w1, const float* __restrict__ w2,
                              unsigned short* __restrict__ Wt) {
    __shared__ float tile[32][33];
    const int m = blockIdx.z;
    const float* src = (m == 0) ? wfc : (m == 1) ? wpj
                     : (m < 10) ? (w1 + (size_t)(m - 2) * C_DIM * C_DIM)
                                : (w2 + (size_t)(m - 10) * C_DIM * C_DIM);
    const int i0 = blockIdx.y * 32;
    const int o0 = blockIdx.x * 32;
    #pragma unroll
    for (int rr = 0; rr < 32; rr += 8)
        tile[threadIdx.y + rr][threadIdx.x] = src[(size_t)(i0 + threadIdx.y + rr) * C_DIM + o0 + threadIdx.x];
    __syncthreads();
    unsigned short* dst = Wt + (size_t)m * C_DIM * C_DIM;
    #pragma unroll
    for (int rr = 0; rr < 32; rr += 8) {
        int o = o0 + threadIdx.y + rr;
        dst[(size_t)o * C_DIM + i0 + threadIdx.x] = f2bf(tile[threadIdx.x][threadIdx.y + rr]);
    }
}

// ---- router pass 1: fp32 logits, sigmoid, top-2 (no atomics); also emits xb = bf16(x) ----
__global__ void router_kernel(const float* __restrict__ x, const float* __restrict__ rw,
                              const float* __restrict__ bias,
                              float* __restrict__ topk_w, int* __restrict__ eids,
                              unsigned short* __restrict__ xb) {
    const int wave = threadIdx.x >> 6;
    const int lane = threadIdx.x & 63;
    const int n = blockIdx.x * 4 + wave;
    const float* xp = x + (size_t)n * C_DIM + lane * 12;
    float xv[12];
    #pragma unroll
    for (int j = 0; j < 12; j++) xv[j] = xp[j];
    unsigned short* xbp = xb + (size_t)n * C_DIM + lane * 12;
    #pragma unroll
    for (int j = 0; j < 12; j++) xbp[j] = f2bf(xv[j]);
    float acc[E_NUM];
    #pragma unroll
    for (int e = 0; e < E_NUM; e++) acc[e] = 0.f;
    #pragma unroll
    for (int e = 0; e < E_NUM; e++) {
        const float* wp = rw + (size_t)e * C_DIM + lane * 12;
        #pragma unroll
        for (int j = 0; j < 12; j++) acc[e] += xv[j] * wp[j];
    }
    #pragma unroll
    for (int e = 0; e < E_NUM; e++) {
        #pragma unroll
        for (int off = 32; off > 0; off >>= 1) acc[e] += __shfl_xor(acc[e], off, 64);
    }
    if (lane == 0) {
        float sc[E_NUM];
        #pragma unroll
        for (int e = 0; e < E_NUM; e++) sc[e] = 1.f / (1.f + expf(-acc[e]));
        int e0 = 0; float best = -1e30f;
        #pragma unroll
        for (int e = 0; e < E_NUM; e++) { float v = sc[e] + bias[e]; if (v > best) { best = v; e0 = e; } }
        int e1 = -1; float best1 = -1e30f;
        #pragma unroll
        for (int e = 0; e < E_NUM; e++) { if (e == e0) continue; float v = sc[e] + bias[e]; if (v > best1) { best1 = v; e1 = e; } }
        float w0 = sc[e0], w1 = sc[e1];
        float s = w0 + w1 + 1e-20f;
        w0 /= s; w1 /= s;
        topk_w[n * 2] = w0; topk_w[n * 2 + 1] = w1;
        eids[n * 2] = e0; eids[n * 2 + 1] = e1;
    }
}

// ---------------- router pass 2: per-expert compaction (deterministic) ----------------
__global__ __launch_bounds__(1024) void bucketize_kernel(const int* __restrict__ eids,
                                                         int* __restrict__ counts,
                                                         int* __restrict__ buckets) {
    const int e = blockIdx.x;
    const int t = threadIdx.x;
    const int wv = t >> 6, lane = t & 63;
    __shared__ int wave_tot[16];
    int running = 0;
    for (int start = 0; start < 2 * N_TOK; start += 1024) {
        const int i = start + t;
        const int f = (eids[i] == e) ? 1 : 0;
        unsigned long long mask = __ballot(f);
        int pre = __popcll(mask & ((1ull << lane) - 1ull));
        if (lane == 0) wave_tot[wv] = __popcll(mask);
        __syncthreads();
        int wbase = 0, tot = 0;
        #pragma unroll
        for (int j = 0; j < 16; j++) { int c = wave_tot[j]; tot += c; if (j < wv) wbase += c; }
        if (f) buckets[e * N_TOK + running + wbase + pre] = i;
        running += tot;
        __syncthreads();
    }
    if (t == 0) counts[e] = running;
}

// ---- block-offset prefix table (256-row units): xoffs[z] = first x-block of expert z ----
__global__ void prefix_kernel(const int* __restrict__ counts, int* __restrict__ xoffs) {
    if (threadIdx.x == 0 && blockIdx.x == 0) {
        int a = 0;
        for (int z = 0; z < E_NUM; z++) { xoffs[z] = a; a += (counts[z] + 255) >> 8; }
        xoffs[E_NUM] = a;            // shared starts here
        xoffs[E_NUM + 1] = a + 32;   // end of work (shared = 8192/256 = 32 blocks)
    }
}

// ------- merged bf16 MFMA GEMM: 256x256 tile, 8 waves, BK=64 double-buffer, 1 barrier/step ----
// PHASE 0 (fc):   A = xb (shared direct; expert gather token=ent>>1); epi relu^2 -> Hsh[n] / H[ent]
// PHASE 1 (proj): A = Hsh (shared) / H gathered by ent (expert);      epi -> out[n] fp32 / Y[ent]
// Rationale (r8 post-mortem): bottleneck = L2->CU staging BW; staged bytes/FLOP ~ (BM+BN)/(BM*BN),
// so 256^2 halves staging traffic per FLOP vs 128^2. Wave tile 128x64 (2x4 wave grid), acc 8x4.
// LDS: 2 x 64 KiB buffers (A 256x64 @0, B 256x64 @16384 ushorts) = 128 KiB -> 1 block/CU, 2 w/SIMD.
// Schedule per step (proven r8): WAITVM(0) [stage issued one compute-phase earlier]; BAR;
// stage(kt+1) -> other buffer; ds_read + 64 MFMA on tile kt. Single barrier is safe (see r8).
// Bank swizzle: 16B slot' = slot ^ (row&7) (full 32-bank spread; zero conflicts measured).
#define GLOAD_LDS(g, l) __builtin_amdgcn_global_load_lds((const __attribute__((address_space(1))) void*)(g), (__attribute__((address_space(3))) void*)(l), 16, 0, 0)
#define WAITVM0() asm volatile("s_waitcnt vmcnt(0)" ::: "memory")
#define SCHEDB() __builtin_amdgcn_sched_barrier(0)
#define BAR() __builtin_amdgcn_s_barrier()

template <int PHASE>
__global__ __launch_bounds__(512, 2) void gemm_all_kernel(const unsigned short* __restrict__ Adir,
                                                          const unsigned short* __restrict__ Agat,
                                                          const unsigned short* __restrict__ WtAll,
                                                          void* __restrict__ dstDir,
                                                          unsigned short* __restrict__ dstGat,
                                                          const int* __restrict__ counts,
                                                          const int* __restrict__ buckets,
                                                          const int* __restrict__ xoffs) {
    // L2-locality decode: xcd-contiguous xx, y innermost
    const int fid = blockIdx.x;
    const int xcd = fid & 7;
    const int i3 = fid >> 3;              // 0..38
    const int xx = xcd * XXP3 + i3 / 3;
    const int y = i3 % 3;
    int xo[10];
    #pragma unroll
    for (int i = 0; i < 10; i++) xo[i] = xoffs[i];
    if (xx >= xo[9]) return;
    int z = E_NUM, xl = xx - xo[8];
    #pragma unroll
    for (int zz = 0; zz < E_NUM; zz++)
        if (xx >= xo[zz] && xx < xo[zz + 1]) { z = zz; xl = xx - xo[zz]; }
    const bool sh = (z == E_NUM);
    const int rows = sh ? N_TOK : counts[z];
    const int r0 = xl * 256;
    const int c0 = y * 256;

    __shared__ __align__(16) unsigned short lds[2 * 32768];   // 128 KiB double buffer

    const int t = threadIdx.x;
    const int lane = t & 63;
    const int wv = t >> 6;
    const int wm = wv >> 2;               // 0..1 -> 128-row half
    const int wn = wv & 3;                // 0..3 -> 64-col quarter

    const int widx = sh ? (PHASE == 0 ? 0 : 1) : (PHASE == 0 ? 2 + z : 10 + z);
    const unsigned short* Bmat = WtAll + (size_t)widx * C_DIM * C_DIM;
    const int* bk = buckets + z * N_TOK;

    // staging: thread t covers rows 64c + (t>>3) (c=0..3), 16B slot t&7 (linear dest t*8 + c*4096),
    // global slot pre-swizzled: (t&7) ^ (row&7), row&7 == (t>>3)&7 (chunks add 64, keep &7)
    const int srow = t >> 3;                                     // 0..63
    const int scol = (((t & 7) ^ ((t >> 3) & 7)) * 8);           // pre-swizzled source col (elems)
    int grow[4];
    const unsigned short* Asrc;
    if (sh) {
        Asrc = Adir;
        #pragma unroll
        for (int c = 0; c < 4; c++) grow[c] = r0 + 64 * c + srow;
    } else {
        Asrc = Agat;
        #pragma unroll
        for (int c = 0; c < 4; c++) {
            int p = r0 + 64 * c + srow;
            int ev = bk[p < rows ? p : 0];
            grow[c] = (PHASE == 0) ? (ev >> 1) : ev;
        }
    }
    const unsigned short* ap[4];
    const unsigned short* bp[4];
    #pragma unroll
    for (int c = 0; c < 4; c++) {
        ap[c] = Asrc + (size_t)grow[c] * C_DIM + scol;
        bp[c] = Bmat + (size_t)(c0 + 64 * c + srow) * C_DIM + scol;
    }

    f32x4 acc[8][4];
    #pragma unroll
    for (int i = 0; i < 8; i++)
        #pragma unroll
        for (int j = 0; j < 4; j++) acc[i][j] = (f32x4){0.f, 0.f, 0.f, 0.f};

    // fragment-read swizzled k-slots: slot = kk*4+fq, row&7 = fr&7
    const int fr = lane & 15;
    const int fq = lane >> 4;
    const int ks0 = ((fq ^ (fr & 7)) * 8);
    const int ks1 = (((4 + fq) ^ (fr & 7)) * 8);

    // prologue: stage tile 0 into buffer 0 (8 vm-ops per thread)
    {
        unsigned short* d = lds + t * 8;
        #pragma unroll
        for (int c = 0; c < 4; c++) {
            GLOAD_LDS(ap[c], d + c * 4096);
            GLOAD_LDS(bp[c], d + 16384 + c * 4096);
        }
    }

    #pragma unroll
    for (int kt = 0; kt < NT2; ++kt) {
        WAITVM0();      // tile kt's loads (issued one full compute-phase ago) complete
        BAR();          // tile kt visible; prior readers of the other buffer are done
        SCHEDB();
        if (kt + 1 < NT2) {
            unsigned short* d = lds + ((kt + 1) & 1) * 32768 + t * 8;
            const int ko = (kt + 1) * 64;
            #pragma unroll
            for (int c = 0; c < 4; c++) {
                GLOAD_LDS(ap[c] + ko, d + c * 4096);
                GLOAD_LDS(bp[c] + ko, d + 16384 + c * 4096);
            }
        }
        SCHEDB();       // stage issued before compute; compute may not hoist above
        const unsigned short* buf = lds + (kt & 1) * 32768;
        short8 bfr[4][2];
        #pragma unroll
        for (int j = 0; j < 4; j++) {
            const unsigned short* rp = buf + 16384 + (size_t)(wn * 64 + j * 16 + fr) * 64;
            bfr[j][0] = *reinterpret_cast<const short8*>(rp + ks0);
            bfr[j][1] = *reinterpret_cast<const short8*>(rp + ks1);
        }
        __builtin_amdgcn_s_setprio(1);
        #pragma unroll
        for (int i = 0; i < 8; i++) {
            const unsigned short* rp = buf + (size_t)(wm * 128 + i * 16 + fr) * 64;
            short8 a0 = *reinterpret_cast<const short8*>(rp + ks0);
            short8 a1 = *reinterpret_cast<const short8*>(rp + ks1);
            #pragma unroll
            for (int j = 0; j < 4; j++)
                acc[i][j] = __builtin_amdgcn_mfma_f32_16x16x32_bf16(
                    __builtin_bit_cast(bf16x8, a0), __builtin_bit_cast(bf16x8, bfr[j][0]), acc[i][j], 0, 0, 0);
            #pragma unroll
            for (int j = 0; j < 4; j++)
                acc[i][j] = __builtin_amdgcn_mfma_f32_16x16x32_bf16(
                    __builtin_bit_cast(bf16x8, a1), __builtin_bit_cast(bf16x8, bfr[j][1]), acc[i][j], 0, 0, 0);
        }
        __builtin_amdgcn_s_setprio(0);
        // single barrier per step: next iteration's stage targets the buffer whose readers
        // all passed this step's BAR before it gets overwritten.
    }

    // ---- epilogue: rows r0 + wm*128 + i*16 + fq*4 + rr; cols c0 + wn*64 + j*16 + fr ----
    const int orow = r0 + wm * 128;
    const int ocol = c0 + wn * 64;
    if (sh) {
        if constexpr (PHASE == 0) {
            unsigned short* Hd = (unsigned short*)dstDir;
            #pragma unroll
            for (int i = 0; i < 8; i++)
                #pragma unroll
                for (int rr = 0; rr < 4; rr++) {
                    size_t base = (size_t)(orow + i * 16 + fq * 4 + rr) * C_DIM;
                    #pragma unroll
                    for (int j = 0; j < 4; j++) {
                        float v = acc[i][j][rr];
                        float rl = v > 0.f ? v : 0.f;
                        Hd[base + ocol + j * 16 + fr] = f2bf(rl * rl);
                    }
                }
        } else {
            float* od = (float*)dstDir;
            #pragma unroll
            for (int i = 0; i < 8; i++)
                #pragma unroll
                for (int rr = 0; rr < 4; rr++) {
                    size_t base = (size_t)(orow + i * 16 + fq * 4 + rr) * C_DIM;
                    #pragma unroll
                    for (int j = 0; j < 4; j++)
                        od[base + ocol + j * 16 + fr] = acc[i][j][rr];
                }
        }
    } else {
        #pragma unroll
        for (int i = 0; i < 8; i++)
            #pragma unroll
            for (int rr = 0; rr < 4; rr++) {
                int pos = orow + i * 16 + fq * 4 + rr;
                if (pos < rows) {
                    int ent = bk[pos];
                    size_t base = (size_t)ent * C_DIM;
                    #pragma unroll
                    for (int j = 0; j < 4; j++) {
                        float v = acc[i][j][rr];
                        if (PHASE == 0) {
                            float rl = v > 0.f ? v : 0.f;
                            dstGat[base + ocol + j * 16 + fr] = f2bf(rl * rl);
                        } else {
                            dstGat[base + ocol + j * 16 + fr] = f2bf(v);
                        }
                    }
                }
            }
    }
}

// ---------------- combine: out += w0*Y[n,0] + w1*Y[n,1] ----------------
__global__ void combine_kernel(float* __restrict__ out, const unsigned short* __restrict__ Y,
                               const float* __restrict__ tw) {
    int idx = blockIdx.x * blockDim.x + threadIdx.x;
    const int per_row = C_DIM / 4;
    if (idx >= N_TOK * per_row) return;
    int n = idx / per_row;
    int c = (idx % per_row) * 4;
    float w0 = tw[n * 2], w1 = tw[n * 2 + 1];
    const ushort4 a = *reinterpret_cast<const ushort4*>(Y + (size_t)(n * 2) * C_DIM + c);
    const ushort4 b = *reinterpret_cast<const ushort4*>(Y + (size_t)(n * 2 + 1) * C_DIM + c);
    float4* op = reinterpret_cast<float4*>(out + (size_t)n * C_DIM + c);
    float4 o = *op;
    o.x += w0 * bf2f(a.x) + w1 * bf2f(b.x);
    o.y += w0 * bf2f(a.y) + w1 * bf2f(b.y);
    o.z += w0 * bf2f(a.z) + w1 * bf2f(b.z);
    o.w += w0 * bf2f(a.w) + w1 * bf2f(b.w);
    *op = o;
}

extern "C" void kernel_launch(void* const* d_in, const int* in_sizes, int n_in,
                              void* d_out, int out_size, void* d_ws, size_t ws_size,
                              hipStream_t stream) {
    const float* x   = (const float*)d_in[0];
    const float* wfc = (const float*)d_in[1];
    const float* wpj = (const float*)d_in[2];
    const float* w1  = (const float*)d_in[3];
    const float* w2  = (const float*)d_in[4];
    const float* rw  = (const float*)d_in[5];
    const float* bias= (const float*)d_in[6];
    float* out = (float*)d_out;

    char* ws = (char*)d_ws;
    size_t off = 0;
    auto alloc = [&](size_t bytes) { void* p = ws + off; off += (bytes + 255) & ~(size_t)255; return p; };
    unsigned short* xb   = (unsigned short*)alloc((size_t)N_TOK * C_DIM * 2);
    unsigned short* Wt   = (unsigned short*)alloc((size_t)18 * C_DIM * C_DIM * 2);
    unsigned short* H    = (unsigned short*)alloc((size_t)N_TOK * 2 * C_DIM * 2);  // expert hidden, by entry
    unsigned short* Hsh  = (unsigned short*)alloc((size_t)N_TOK * C_DIM * 2);      // shared hidden
    unsigned short* Y    = (unsigned short*)alloc((size_t)N_TOK * 2 * C_DIM * 2);  // expert out, by entry
    float* topk_w        = (float*)alloc((size_t)N_TOK * 2 * 4);
    int* counts          = (int*)alloc(256);
    int* buckets         = (int*)alloc((size_t)E_NUM * N_TOK * 4);
    int* eids            = (int*)alloc((size_t)2 * N_TOK * 4);
    int* xoffs           = (int*)alloc(64);

    wtrans_kernel<<<dim3(24, 24, 18), dim3(32, 8), 0, stream>>>(wfc, wpj, w1, w2, Wt);
    router_kernel<<<N_TOK / 4, 256, 0, stream>>>(x, rw, bias, topk_w, eids, xb);
    bucketize_kernel<<<E_NUM, 1024, 0, stream>>>(eids, counts, buckets);
    prefix_kernel<<<1, 64, 0, stream>>>(counts, xoffs);

    gemm_all_kernel<0><<<GRID3, 512, 0, stream>>>(xb, xb, Wt, Hsh, H, counts, buckets, xoffs);
    gemm_all_kernel<1><<<GRID3, 512, 0, stream>>>(Hsh, H, Wt, out, Y, counts, buckets, xoffs);

    combine_kernel<<<(N_TOK * (C_DIM / 4) + 255) / 256, 256, 0, stream>>>(out, Y, topk_w);
}